// Round 5
// baseline (263.219 us; speedup 1.0000x reference)
//
#include <hip/hip_runtime.h>
#include <hip/hip_bf16.h>
#include <stdint.h>

// Problem constants (fixed by reference)
#define T_TASKS 8
#define DM      1024
#define HID     1024
#define NC      100
#define NCP     128
#define BATCH   8192
#define MPAD    9216      // 8192 + 8*128 worst-case 128-aligned padding
#define MT      (MPAD/16) // 576 m-tiles of 16 rows

typedef __bf16 bf16x8 __attribute__((ext_vector_type(8)));
typedef float  f32x4  __attribute__((ext_vector_type(4)));

__device__ __forceinline__ unsigned short f2bf(float f) {
  __hip_bfloat16 h = __float2bfloat16(f);
  return __builtin_bit_cast(unsigned short, h);
}

// Fragment-packed layouts (for v_mfma_f32_16x16x32_bf16, lane l: outer=l&15,
// k = (l>>4)*8 + j):
//   XF  frag(mt, kc): XF[((mt*32+kc)*64 + lane)*8 + j] = X[m=mt*16+(l&15)][k]
//   W1F frag(t, ht, kc): same, outer = h (n of mm1), k = d
//   W2F frag(t, ci, kc): outer = c (n of mm2), k = h
// => every GEMM operand load is global_load_dwordx4 at base + lane*16B:
//    one contiguous 1KB segment per instruction, no LDS, no barrier.

// ---------------------------------------------------------------------------
// init: zero d_out (atomic target), perm = -1, gmeta = 0.
// ---------------------------------------------------------------------------
__global__ void init_k(float* __restrict__ out, int* __restrict__ perm,
                       int* __restrict__ gmeta) {
  const int gid = blockIdx.x * 256 + threadIdx.x;
  const uint4 z  = {0u, 0u, 0u, 0u};
  const uint4 m1 = {0xFFFFFFFFu, 0xFFFFFFFFu, 0xFFFFFFFFu, 0xFFFFFFFFu};
  uint4* o4 = (uint4*)out;
  for (int i = gid; i < (BATCH * NC) / 4; i += 512 * 256) o4[i] = z;
  uint4* p4 = (uint4*)perm;
  for (int i = gid; i < MPAD / 4; i += 512 * 256) p4[i] = m1;
  if (gid < 16) gmeta[gid] = 0;
}

// ---------------------------------------------------------------------------
// count: per-block LDS histogram -> 8 global atomics. grid 32 x 256.
// ---------------------------------------------------------------------------
__global__ void count_k(const int* __restrict__ task_id, int* __restrict__ gmeta) {
  __shared__ int h[T_TASKS];
  const int tid = threadIdx.x;
  if (tid < T_TASKS) h[tid] = 0;
  __syncthreads();
  atomicAdd(&h[task_id[blockIdx.x * 256 + tid]], 1);
  __syncthreads();
  if (tid < T_TASKS) atomicAdd(&gmeta[tid], h[tid]);
}

// ---------------------------------------------------------------------------
// scatter: starts from complete gcnt; per-block local slots + one global
// range reservation per task per block. grid 32 x 256.
// ---------------------------------------------------------------------------
__global__ void scatter_k(const int* __restrict__ task_id, int* __restrict__ gmeta,
                          int* __restrict__ perm, int* __restrict__ starts) {
  __shared__ int h[T_TASKS];
  __shared__ int base[T_TASKS];
  __shared__ int sst[T_TASKS + 1];
  const int tid = threadIdx.x;
  if (tid < T_TASKS) h[tid] = 0;
  if (tid == 0) {
    int off = 0;
    for (int t = 0; t < T_TASKS; ++t) {
      sst[t] = off;
      off += (gmeta[t] + 127) & ~127;
    }
    sst[T_TASKS] = off;
  }
  __syncthreads();
  const int r = blockIdx.x * 256 + tid;
  const int t = task_id[r];
  const int slot = atomicAdd(&h[t], 1);
  __syncthreads();
  if (tid < T_TASKS) base[tid] = atomicAdd(&gmeta[8 + tid], h[tid]);
  __syncthreads();
  perm[sst[t] + base[t] + slot] = r;
  if (blockIdx.x == 0 && tid <= T_TASKS) starts[tid] = sst[tid];
}

// ---------------------------------------------------------------------------
// gather x rows -> fragment-packed bf16 XF (zeros for pads).
// grid 144 x 256 (4 waves, wave w handles m-tile blockIdx.x*4+w).
// ---------------------------------------------------------------------------
__global__ void gather_x_packed(const float* __restrict__ x,
                                const int* __restrict__ perm,
                                unsigned short* __restrict__ XF) {
  const int tid  = threadIdx.x;
  const int mi   = blockIdx.x * 4 + (tid >> 6);
  const int lane = tid & 63;
  const int lr   = lane & 15;
  const int quad = lane >> 4;
  const int r    = perm[mi * 16 + lr];
  unsigned short* dst = XF + (size_t)mi * 32 * 512 + lane * 8;
  const float* src = x + (size_t)(r < 0 ? 0 : r) * DM + quad * 8;
#pragma unroll 4
  for (int kc = 0; kc < 32; ++kc) {
    union { uint4 v; unsigned short s[8]; } o;
    if (r >= 0) {
      const float4 f0 = *(const float4*)(src + kc * 32);
      const float4 f1 = *(const float4*)(src + kc * 32 + 4);
      o.s[0] = f2bf(f0.x); o.s[1] = f2bf(f0.y); o.s[2] = f2bf(f0.z); o.s[3] = f2bf(f0.w);
      o.s[4] = f2bf(f1.x); o.s[5] = f2bf(f1.y); o.s[6] = f2bf(f1.z); o.s[7] = f2bf(f1.w);
    } else {
      o.v = (uint4){0u, 0u, 0u, 0u};
    }
    *(uint4*)(dst + kc * 512) = o.v;
  }
}

// ---------------------------------------------------------------------------
// W1 [t][d][h] fp32 -> W1F fragment-packed bf16. grid (16 d, 16 h, 8 t) x 256.
// LDS tile [h][d] (stride 72, 16B-aligned rows), then each wave emits 2 frags
// as coalesced 1KB stores.
// ---------------------------------------------------------------------------
__global__ void transpose_w1_packed(const float* __restrict__ W1,
                                    unsigned short* __restrict__ W1F) {
  __shared__ unsigned short tile[64 * 72];
  const int t  = blockIdx.z;
  const int d0 = blockIdx.x * 64;
  const int h0 = blockIdx.y * 64;
  const int tid = threadIdx.x;
  const float* src = W1 + (size_t)t * DM * HID;
#pragma unroll
  for (int i = 0; i < 16; ++i) {
    const int idx = tid + 256 * i;
    const int ld = idx >> 6, lh = idx & 63;       // read coalesced over h
    tile[lh * 72 + ld] = f2bf(src[(size_t)(d0 + ld) * HID + h0 + lh]);
  }
  __syncthreads();
  const int w = tid >> 6, lane = tid & 63;
  const int lr = lane & 15, quad = lane >> 4;
#pragma unroll
  for (int kcl = 0; kcl < 2; ++kcl) {
    const uint4 v = *(const uint4*)&tile[(w * 16 + lr) * 72 + kcl * 32 + quad * 8];
    unsigned short* dst =
        W1F + (((size_t)t * 64 + (h0 >> 4) + w) * 32 + (d0 >> 5) + kcl) * 512 + lane * 8;
    *(uint4*)dst = v;
  }
}

// ---------------------------------------------------------------------------
// W2 [t][h][c<100] fp32 -> W2F fragment-packed bf16 (c padded to 128).
// grid (16 h-tiles, 8 t) x 256.
// ---------------------------------------------------------------------------
__global__ void transpose_w2_packed(const float* __restrict__ W2,
                                    unsigned short* __restrict__ W2F) {
  __shared__ unsigned short tile[128 * 72];
  const int t  = blockIdx.y;
  const int h0 = blockIdx.x * 64;
  const int tid = threadIdx.x;
  const float* src = W2 + (size_t)t * HID * NC;
#pragma unroll
  for (int i = 0; i < 36; ++i) tile[tid + 256 * i] = 0;   // 9216 exact
  __syncthreads();
#pragma unroll
  for (int i = 0; i < 32; ++i) {
    const int idx = tid + 256 * i;                 // 64 rows x 128 cols
    const int row = idx >> 7, col = idx & 127;
    if (col < NC)
      tile[col * 72 + row] = f2bf(src[(size_t)(h0 + row) * NC + col]);
  }
  __syncthreads();
  const int w = tid >> 6, lane = tid & 63;
  const int lr = lane & 15, quad = lane >> 4;
#pragma unroll
  for (int e = 0; e < 4; ++e) {
    const int fi = w * 4 + e;                      // 0..15
    const int ci = fi >> 1, kcl = fi & 1;
    const uint4 v = *(const uint4*)&tile[(ci * 16 + lr) * 72 + kcl * 32 + quad * 8];
    unsigned short* dst =
        W2F + (((size_t)t * 8 + ci) * 32 + (h0 >> 5) + kcl) * 512 + lane * 8;
    *(uint4*)dst = v;
  }
}

// ---------------------------------------------------------------------------
// Fused MLP: one wave per block, 64(m) x 64(n of mm1) tile, NO barriers in
// the K-loop, all operand loads are coalesced 1KB fragment loads with
// register double-buffering (compiler schedules fine-grained vmcnt).
// grid (144, 16). After mm1: +b1/relu -> private LDS round-trip (C->A layout)
// -> mm2 vs W2F k-slice [by*64, by*64+64) -> atomic partial scatter to out.
// ---------------------------------------------------------------------------
__global__ __launch_bounds__(64, 2) void mlp_fused(
    const unsigned short* __restrict__ XF,     // frag-packed [MT][32][512]
    const unsigned short* __restrict__ W1F,    // frag-packed [T][64][32][512]
    const unsigned short* __restrict__ W2F,    // frag-packed [T][8][32][512]
    const float* __restrict__ b1,              // [T][HID]
    const float* __restrict__ b2,              // [T][NC]
    const int* __restrict__ starts,            // [9]
    const int* __restrict__ perm,              // [MPAD]
    float* __restrict__ Out)                   // [BATCH][NC] fp32 (zeroed)
{
  __shared__ unsigned short hS[64 * 72];       // 9 KB private to this wave
  const int lane = threadIdx.x;
  const int lr   = lane & 15;
  const int quad = lane >> 4;
  const int bx = blockIdx.x, by = blockIdx.y;
  const int p0 = bx * 64;

  int task = 0;
#pragma unroll
  for (int t = 1; t < T_TASKS; ++t)
    if (p0 >= starts[t]) task = t;

  const unsigned short* pA = XF + ((size_t)bx * 4 * 32) * 512 + lane * 8;
  const unsigned short* pB = W1F + (((size_t)task * 64 + by * 4) * 32) * 512 + lane * 8;

  f32x4 acc[4][4];
#pragma unroll
  for (int i = 0; i < 4; ++i)
#pragma unroll
    for (int j = 0; j < 4; ++j) acc[i][j] = (f32x4){0.f, 0.f, 0.f, 0.f};

  bf16x8 a0[4], b0[4], a1[4], b1r[4];
  auto load_stage = [&](bf16x8* a, bf16x8* b, int kc) {
#pragma unroll
    for (int i = 0; i < 4; ++i) a[i] = *(const bf16x8*)(pA + ((size_t)i * 32 + kc) * 512);
#pragma unroll
    for (int j = 0; j < 4; ++j) b[j] = *(const bf16x8*)(pB + ((size_t)j * 32 + kc) * 512);
  };
  load_stage(a0, b0, 0);
  for (int kc = 0; kc < 32; kc += 2) {
    load_stage(a1, b1r, kc + 1);
#pragma unroll
    for (int i = 0; i < 4; ++i)
#pragma unroll
      for (int j = 0; j < 4; ++j)
        acc[i][j] = __builtin_amdgcn_mfma_f32_16x16x32_bf16(a0[i], b0[j], acc[i][j], 0, 0, 0);
    if (kc < 30) load_stage(a0, b0, kc + 2);
#pragma unroll
    for (int i = 0; i < 4; ++i)
#pragma unroll
      for (int j = 0; j < 4; ++j)
        acc[i][j] = __builtin_amdgcn_mfma_f32_16x16x32_bf16(a1[i], b1r[j], acc[i][j], 0, 0, 0);
  }

  // --- prefetch W2 fragments (mm2 B-operand, k-slice = this block's n0) ---
  bf16x8 w2f[8][2];
  const unsigned short* pW2 = W2F + ((size_t)task * 8 * 32 + by * 2) * 512 + lane * 8;
#pragma unroll
  for (int ci = 0; ci < 8; ++ci)
#pragma unroll
    for (int e = 0; e < 2; ++e)
      w2f[ci][e] = *(const bf16x8*)(pW2 + ((size_t)ci * 32 + e) * 512);

  int orig[4][4];
#pragma unroll
  for (int i = 0; i < 4; ++i)
#pragma unroll
    for (int r = 0; r < 4; ++r)
      orig[i][r] = perm[p0 + i * 16 + quad * 4 + r];

  // --- h = relu(acc + b1) -> bf16 -> LDS (C-layout in, A-layout out) ---
  const float* bv = b1 + (size_t)task * HID + by * 64;
  float bj[4];
#pragma unroll
  for (int j = 0; j < 4; ++j) bj[j] = bv[j * 16 + lr];
#pragma unroll
  for (int i = 0; i < 4; ++i)
#pragma unroll
    for (int r = 0; r < 4; ++r) {
      const int row = i * 16 + quad * 4 + r;
#pragma unroll
      for (int j = 0; j < 4; ++j) {
        float v = acc[i][j][r] + bj[j];
        v = v > 0.f ? v : 0.f;
        hS[row * 72 + j * 16 + lr] = f2bf(v);
      }
    }
  __syncthreads();   // single wave: just an LDS ordering fence

  bf16x8 a2[4][2];
#pragma unroll
  for (int i = 0; i < 4; ++i)
#pragma unroll
    for (int e = 0; e < 2; ++e)
      a2[i][e] = *(const bf16x8*)&hS[(i * 16 + lr) * 72 + e * 32 + quad * 8];

  // --- mm2 halves (bound VGPR) + atomic partial scatter ---
  const float* bv2 = b2 + (size_t)task * NC;
#pragma unroll
  for (int half = 0; half < 2; ++half) {
    f32x4 acc2[4][4];
#pragma unroll
    for (int i = 0; i < 4; ++i)
#pragma unroll
      for (int c = 0; c < 4; ++c) acc2[i][c] = (f32x4){0.f, 0.f, 0.f, 0.f};
#pragma unroll
    for (int e = 0; e < 2; ++e)
#pragma unroll
      for (int i = 0; i < 4; ++i)
#pragma unroll
        for (int c = 0; c < 4; ++c)
          acc2[i][c] = __builtin_amdgcn_mfma_f32_16x16x32_bf16(
              a2[i][e], w2f[half * 4 + c][e], acc2[i][c], 0, 0, 0);
#pragma unroll
    for (int i = 0; i < 4; ++i)
#pragma unroll
      for (int r = 0; r < 4; ++r) {
        const int og = orig[i][r];
        if (og < 0) continue;
#pragma unroll
        for (int c = 0; c < 4; ++c) {
          const int col = (half * 4 + c) * 16 + lr;
          if (col < NC) {
            float v = acc2[i][c][r];
            if (by == 0) v += bv2[col];
            unsafeAtomicAdd(&Out[(size_t)og * NC + col], v);
          }
        }
      }
  }
}

// ---------------------------------------------------------------------------
// Workspace layout (bytes):
//   perm   int[9216]            @ 0           (36864)
//   gmeta  int[16]              @ 36864
//   starts int[9]               @ 36928
//   XF     bf16[576*32*512]     @ 65536       (18874368)
//   W1F    bf16[8*64*32*512]    @ 18939904    (16777216)
//   W2F    bf16[8*8*32*512]     @ 35717120    (2097152)   end 37814272
// ---------------------------------------------------------------------------
extern "C" void kernel_launch(void* const* d_in, const int* in_sizes, int n_in,
                              void* d_out, int out_size, void* d_ws, size_t ws_size,
                              hipStream_t stream) {
  const float* x       = (const float*)d_in[0];
  const int*   task_id = (const int*)d_in[1];
  const float* W1      = (const float*)d_in[2];
  const float* b1      = (const float*)d_in[3];
  const float* W2      = (const float*)d_in[4];
  const float* b2      = (const float*)d_in[5];
  float* out = (float*)d_out;

  char* ws = (char*)d_ws;
  int* perm   = (int*)(ws + 0);
  int* gmeta  = (int*)(ws + 36864);
  int* starts = (int*)(ws + 36928);
  unsigned short* XF  = (unsigned short*)(ws + 65536);
  unsigned short* W1F = (unsigned short*)(ws + 18939904);
  unsigned short* W2F = (unsigned short*)(ws + 35717120);

  init_k<<<512, 256, 0, stream>>>(out, perm, gmeta);
  count_k<<<32, 256, 0, stream>>>(task_id, gmeta);
  scatter_k<<<32, 256, 0, stream>>>(task_id, gmeta, perm, starts);
  gather_x_packed<<<144, 256, 0, stream>>>(x, perm, XF);
  transpose_w1_packed<<<dim3(16, 16, T_TASKS), 256, 0, stream>>>(W1, W1F);
  transpose_w2_packed<<<dim3(16, T_TASKS), 256, 0, stream>>>(W2, W2F);
  mlp_fused<<<dim3(MT / 4, 16), 64, 0, stream>>>(
      XF, W1F, W2F, b1, b2, starts, perm, out);
}

// Round 6
// 262.932 us; speedup vs baseline: 1.0011x; 1.0011x over previous
//
#include <hip/hip_runtime.h>
#include <hip/hip_bf16.h>
#include <stdint.h>

// Problem constants (fixed by reference)
#define T_TASKS 8
#define DM      1024
#define HID     1024
#define NC      100
#define NCP     128
#define BATCH   8192
#define MPAD    9216      // 8192 + 8*128 worst-case 128-aligned padding

typedef __bf16 bf16x8 __attribute__((ext_vector_type(8)));
typedef float  f32x4  __attribute__((ext_vector_type(4)));

__device__ __forceinline__ unsigned short f2bf(float f) {
  __hip_bfloat16 h = __float2bfloat16(f);
  return __builtin_bit_cast(unsigned short, h);
}

// Barrier WITHOUT vmcnt drain: only LDS ops must complete. Global loads
// issued before this stay in flight across it (CK block_sync_lds idiom).
__device__ __forceinline__ void lds_barrier() {
  asm volatile("s_waitcnt lgkmcnt(0)\n\ts_barrier" ::: "memory");
}

// ---------------------------------------------------------------------------
// init: zero d_out (atomic target), perm = -1, gmeta = 0.
// ---------------------------------------------------------------------------
__global__ void init_k(float* __restrict__ out, int* __restrict__ perm,
                       int* __restrict__ gmeta) {
  const int gid = blockIdx.x * 256 + threadIdx.x;
  const uint4 z  = {0u, 0u, 0u, 0u};
  const uint4 m1 = {0xFFFFFFFFu, 0xFFFFFFFFu, 0xFFFFFFFFu, 0xFFFFFFFFu};
  uint4* o4 = (uint4*)out;
  for (int i = gid; i < (BATCH * NC) / 4; i += 512 * 256) o4[i] = z;
  uint4* p4 = (uint4*)perm;
  for (int i = gid; i < MPAD / 4; i += 512 * 256) p4[i] = m1;
  if (gid < 16) gmeta[gid] = 0;
}

// ---------------------------------------------------------------------------
// count: per-block LDS histogram -> 8 global atomics. grid 32 x 256.
// ---------------------------------------------------------------------------
__global__ void count_k(const int* __restrict__ task_id, int* __restrict__ gmeta) {
  __shared__ int h[T_TASKS];
  const int tid = threadIdx.x;
  if (tid < T_TASKS) h[tid] = 0;
  __syncthreads();
  atomicAdd(&h[task_id[blockIdx.x * 256 + tid]], 1);
  __syncthreads();
  if (tid < T_TASKS) atomicAdd(&gmeta[tid], h[tid]);
}

// ---------------------------------------------------------------------------
// scatter: starts from complete gcnt; per-block local slots + one global
// range reservation per task per block. grid 32 x 256.
// ---------------------------------------------------------------------------
__global__ void scatter_k(const int* __restrict__ task_id, int* __restrict__ gmeta,
                          int* __restrict__ perm, int* __restrict__ starts) {
  __shared__ int h[T_TASKS];
  __shared__ int base[T_TASKS];
  __shared__ int sst[T_TASKS + 1];
  const int tid = threadIdx.x;
  if (tid < T_TASKS) h[tid] = 0;
  if (tid == 0) {
    int off = 0;
    for (int t = 0; t < T_TASKS; ++t) {
      sst[t] = off;
      off += (gmeta[t] + 127) & ~127;
    }
    sst[T_TASKS] = off;
  }
  __syncthreads();
  const int r = blockIdx.x * 256 + tid;
  const int t = task_id[r];
  const int slot = atomicAdd(&h[t], 1);
  __syncthreads();
  if (tid < T_TASKS) base[tid] = atomicAdd(&gmeta[8 + tid], h[tid]);
  __syncthreads();
  perm[sst[t] + base[t] + slot] = r;
  if (blockIdx.x == 0 && tid <= T_TASKS) starts[tid] = sst[tid];
}

// ---------------------------------------------------------------------------
// gather+convert x rows into permuted bf16 XP (zeros for pads). grid MPAD x 256.
// ---------------------------------------------------------------------------
__global__ void gather_x(const float* __restrict__ x,
                         const int* __restrict__ perm,
                         unsigned short* __restrict__ XP) {
  const int p = blockIdx.x;
  const int r = perm[p];
  const int c = threadIdx.x * 4;
  ushort4 v;
  if (r >= 0) {
    const float4 f = *(const float4*)(x + (size_t)r * DM + c);
    v.x = f2bf(f.x); v.y = f2bf(f.y); v.z = f2bf(f.z); v.w = f2bf(f.w);
  } else {
    v.x = 0; v.y = 0; v.z = 0; v.w = 0;
  }
  *(ushort4*)(XP + (size_t)p * DM + c) = v;
}

// ---------------------------------------------------------------------------
// W1 [t][d][h] fp32 -> W1T [t][h][d] bf16  (LDS-tiled 64x64)
// ---------------------------------------------------------------------------
__global__ void transpose_w1(const float* __restrict__ W1,
                             unsigned short* __restrict__ W1T) {
  __shared__ unsigned short tile[64][65];
  const int t  = blockIdx.z;
  const int d0 = blockIdx.x * 64;
  const int h0 = blockIdx.y * 64;
  const int tid = threadIdx.x;
  const float* src = W1 + (size_t)t * DM * HID;
  unsigned short* dst = W1T + (size_t)t * HID * DM;
#pragma unroll
  for (int i = 0; i < 16; ++i) {
    int idx = tid + 256 * i;
    int ld = idx >> 6, lh = idx & 63;
    tile[lh][ld] = f2bf(src[(size_t)(d0 + ld) * HID + h0 + lh]);
  }
  __syncthreads();
#pragma unroll
  for (int i = 0; i < 16; ++i) {
    int idx = tid + 256 * i;
    int lh = idx >> 6, ld = idx & 63;
    dst[(size_t)(h0 + lh) * DM + d0 + ld] = tile[lh][ld];
  }
}

// ---------------------------------------------------------------------------
// W2 [t][h][c<100] fp32 -> W2F fragment-packed bf16 (c padded to 128).
// frag(t, ci, kc): lane l holds c = ci*16+(l&15), h = kc*32+(l>>4)*8+j.
// grid (16 h-tiles, 8 t) x 256.  (verified correct in round 5)
// ---------------------------------------------------------------------------
__global__ void transpose_w2_packed(const float* __restrict__ W2,
                                    unsigned short* __restrict__ W2F) {
  __shared__ unsigned short tile[128 * 72];
  const int t  = blockIdx.y;
  const int h0 = blockIdx.x * 64;
  const int tid = threadIdx.x;
  const float* src = W2 + (size_t)t * HID * NC;
#pragma unroll
  for (int i = 0; i < 36; ++i) tile[tid + 256 * i] = 0;
  __syncthreads();
#pragma unroll
  for (int i = 0; i < 32; ++i) {
    const int idx = tid + 256 * i;
    const int row = idx >> 7, col = idx & 127;
    if (col < NC)
      tile[col * 72 + row] = f2bf(src[(size_t)(h0 + row) * NC + col]);
  }
  __syncthreads();
  const int w = tid >> 6, lane = tid & 63;
  const int lr = lane & 15, quad = lane >> 4;
#pragma unroll
  for (int e = 0; e < 4; ++e) {
    const int fi = w * 4 + e;
    const int ci = fi >> 1, kcl = fi & 1;
    const uint4 v = *(const uint4*)&tile[(ci * 16 + lr) * 72 + kcl * 32 + quad * 8];
    unsigned short* dst =
        W2F + (((size_t)t * 8 + ci) * 32 + (h0 >> 5) + kcl) * 512 + lane * 8;
    *(uint4*)dst = v;
  }
}

// ---------------------------------------------------------------------------
// Fused MLP GEMM, register-prefetch pipeline. grid (72, 8), 256 thr = 4 waves.
// Tile 128(m) x 128(n of mm1), BK=64. Per iter: ds_write staged regs -> issue
// global loads for next tile (STAY IN FLIGHT across barrier: lds_barrier has
// no vmcnt wait) -> 32 MFMAs/wave from LDS -> lds_barrier. LDS stride 72
// (2-way bank alias max = free). After mm1: relu+b1 -> hS (C->A layout) ->
// mm2 vs frag-packed W2F (k-slice = this block's n-range) -> atomic partial
// scatter to out via perm (+b2 on by==0). No HB buffer, no __syncthreads.
// ---------------------------------------------------------------------------
__global__ __launch_bounds__(256, 3) void gemm_fused2(
    const unsigned short* __restrict__ XP,     // [MPAD][1024] bf16 permuted
    const unsigned short* __restrict__ W1T,    // [T][HID][1024] bf16
    const unsigned short* __restrict__ W2F,    // [T][8][32][512] frag-packed
    const float* __restrict__ b1,              // [T][HID]
    const float* __restrict__ b2,              // [T][NC]
    const int* __restrict__ starts,            // [9]
    const int* __restrict__ perm,              // [MPAD]
    float* __restrict__ Out)                   // [BATCH][NC] fp32 (zeroed)
{
  __shared__ __align__(16) unsigned short lds[18432];   // 36 KB
  unsigned short* As = lds;                    // [128][72]
  unsigned short* Bs = lds + 9216;             // [128][72]
  unsigned short* hS = lds;                    // reuse: [128][136] = 17408 shorts

  const int tid = threadIdx.x;
  const int p0  = blockIdx.x * 128;
  const int n0  = blockIdx.y * 128;

  int task = 0;
#pragma unroll
  for (int t = 1; t < T_TASKS; ++t)
    if (p0 >= starts[t]) task = t;

  const int wave = tid >> 6;
  const int lane = tid & 63;
  const int wm   = (wave >> 1) * 64;
  const int wn   = (wave & 1) * 64;
  const int lr   = lane & 15;
  const int quad = lane >> 4;

  // staging geometry: 4 chunks each of A and B per thread (16B chunks)
  const int srow = tid >> 3;                   // 0..31
  const int scol = tid & 7;
  unsigned aoff[4], boff[4];
  int loff[4];
#pragma unroll
  for (int i = 0; i < 4; ++i) {
    const int row = srow + 32 * i;
    aoff[i] = (unsigned)((p0 + row) * 1024 + scol * 8);
    boff[i] = (unsigned)((task * 1024 + n0 + row) * 1024 + scol * 8);
    loff[i] = row * 72 + scol * 8;
  }

  // b1 preload (per-lane cols of this wave's n-slice)
  float b1v[4];
#pragma unroll
  for (int ni = 0; ni < 4; ++ni)
    b1v[ni] = b1[task * HID + n0 + wn + ni * 16 + lr];

  f32x4 acc[4][4];
#pragma unroll
  for (int i = 0; i < 4; ++i)
#pragma unroll
    for (int j = 0; j < 4; ++j) acc[i][j] = (f32x4){0.f, 0.f, 0.f, 0.f};

  uint4 rA[4], rB[4];
#pragma unroll
  for (int i = 0; i < 4; ++i) {
    rA[i] = *(const uint4*)(XP + aoff[i]);
    rB[i] = *(const uint4*)(W1T + boff[i]);
  }

  for (int k0 = 0; k0 < 1024; k0 += 64) {
#pragma unroll
    for (int i = 0; i < 4; ++i) {
      *(uint4*)&As[loff[i]] = rA[i];
      *(uint4*)&Bs[loff[i]] = rB[i];
    }
    if (k0 < 960) {                            // prefetch next tile; in flight
#pragma unroll                                 // across the lds_barrier below
      for (int i = 0; i < 4; ++i) {
        rA[i] = *(const uint4*)(XP + aoff[i] + k0 + 64);
        rB[i] = *(const uint4*)(W1T + boff[i] + k0 + 64);
      }
    }
    lds_barrier();
#pragma unroll
    for (int kk = 0; kk < 2; ++kk) {
      bf16x8 a[4], b[4];
#pragma unroll
      for (int mi = 0; mi < 4; ++mi)
        a[mi] = *(const bf16x8*)&As[(wm + mi * 16 + lr) * 72 + kk * 32 + quad * 8];
#pragma unroll
      for (int ni = 0; ni < 4; ++ni)
        b[ni] = *(const bf16x8*)&Bs[(wn + ni * 16 + lr) * 72 + kk * 32 + quad * 8];
#pragma unroll
      for (int mi = 0; mi < 4; ++mi)
#pragma unroll
        for (int ni = 0; ni < 4; ++ni)
          acc[mi][ni] = __builtin_amdgcn_mfma_f32_16x16x32_bf16(a[mi], b[ni], acc[mi][ni], 0, 0, 0);
    }
    lds_barrier();
  }

  // --- perm rows for scatter ---
  int orig[4][4];
#pragma unroll
  for (int mi = 0; mi < 4; ++mi)
#pragma unroll
    for (int r = 0; r < 4; ++r)
      orig[mi][r] = perm[p0 + wm + mi * 16 + quad * 4 + r];

  // --- h = relu(acc + b1) -> bf16 -> hS (each wave its own 64x64 quadrant) ---
#pragma unroll
  for (int mi = 0; mi < 4; ++mi)
#pragma unroll
    for (int r = 0; r < 4; ++r) {
      const int row = wm + mi * 16 + quad * 4 + r;
#pragma unroll
      for (int ni = 0; ni < 4; ++ni) {
        float v = acc[mi][ni][r] + b1v[ni];
        v = v > 0.f ? v : 0.f;
        hS[row * 136 + wn + ni * 16 + lr] = f2bf(v);
      }
    }
  lds_barrier();

  // --- mm2: h[128 x 128-slice] x W2F k-slice -> 128x128 partial logits ---
  // wave handles rows [wm,wm+64) x classes [wn,wn+64); ci base = wn/16.
  const int cbase = (wave & 1) * 4;
  const unsigned short* pW2 =
      W2F + (((size_t)task * 8 + cbase) * 32 + blockIdx.y * 4) * 512 + lane * 8;

  f32x4 acc2[4][4];
#pragma unroll
  for (int mi = 0; mi < 4; ++mi)
#pragma unroll
    for (int ci = 0; ci < 4; ++ci) acc2[mi][ci] = (f32x4){0.f, 0.f, 0.f, 0.f};

  bf16x8 w2p[2][4];
#pragma unroll
  for (int ci = 0; ci < 4; ++ci)
    w2p[0][ci] = *(const bf16x8*)(pW2 + (ci * 32 + 0) * 512);
#pragma unroll
  for (int e = 0; e < 4; ++e) {
    if (e < 3) {
#pragma unroll
      for (int ci = 0; ci < 4; ++ci)
        w2p[(e + 1) & 1][ci] = *(const bf16x8*)(pW2 + ((size_t)ci * 32 + e + 1) * 512);
    }
    bf16x8 a2[4];
#pragma unroll
    for (int mi = 0; mi < 4; ++mi)
      a2[mi] = *(const bf16x8*)&hS[(wm + mi * 16 + lr) * 136 + e * 32 + quad * 8];
#pragma unroll
    for (int mi = 0; mi < 4; ++mi)
#pragma unroll
      for (int ci = 0; ci < 4; ++ci)
        acc2[mi][ci] = __builtin_amdgcn_mfma_f32_16x16x32_bf16(
            a2[mi], w2p[e & 1][ci], acc2[mi][ci], 0, 0, 0);
  }

  // --- atomic partial scatter to out; +b2 once (by==0) ---
  const float* bv2 = b2 + (size_t)task * NC;
  const bool addb = (blockIdx.y == 0);
#pragma unroll
  for (int mi = 0; mi < 4; ++mi)
#pragma unroll
    for (int r = 0; r < 4; ++r) {
      const int og = orig[mi][r];
      if (og < 0) continue;
#pragma unroll
      for (int ci = 0; ci < 4; ++ci) {
        const int col = wn + ci * 16 + lr;
        if (col < NC) {
          float v = acc2[mi][ci][r];
          if (addb) v += bv2[col];
          unsafeAtomicAdd(&Out[(size_t)og * NC + col], v);
        }
      }
    }
}

// ---------------------------------------------------------------------------
// Workspace layout (bytes):
//   perm   int[9216]            @ 0           (36864)
//   gmeta  int[16]              @ 36864
//   starts int[9]               @ 36928
//   XP     bf16[9216*1024]      @ 65536       (18874368)
//   W1T    bf16[8*1024*1024]    @ 18939904    (16777216)
//   W2F    bf16[8*8*32*512]     @ 35717120    (2097152)   end 37814272
// ---------------------------------------------------------------------------
extern "C" void kernel_launch(void* const* d_in, const int* in_sizes, int n_in,
                              void* d_out, int out_size, void* d_ws, size_t ws_size,
                              hipStream_t stream) {
  const float* x       = (const float*)d_in[0];
  const int*   task_id = (const int*)d_in[1];
  const float* W1      = (const float*)d_in[2];
  const float* b1      = (const float*)d_in[3];
  const float* W2      = (const float*)d_in[4];
  const float* b2      = (const float*)d_in[5];
  float* out = (float*)d_out;

  char* ws = (char*)d_ws;
  int* perm   = (int*)(ws + 0);
  int* gmeta  = (int*)(ws + 36864);
  int* starts = (int*)(ws + 36928);
  unsigned short* XP  = (unsigned short*)(ws + 65536);
  unsigned short* W1T = (unsigned short*)(ws + 18939904);
  unsigned short* W2F = (unsigned short*)(ws + 35717120);

  init_k<<<512, 256, 0, stream>>>(out, perm, gmeta);
  count_k<<<32, 256, 0, stream>>>(task_id, gmeta);
  scatter_k<<<32, 256, 0, stream>>>(task_id, gmeta, perm, starts);
  gather_x<<<MPAD, 256, 0, stream>>>(x, perm, XP);
  transpose_w1<<<dim3(16, 16, T_TASKS), 256, 0, stream>>>(W1, W1T);
  transpose_w2_packed<<<dim3(16, T_TASKS), 256, 0, stream>>>(W2, W2F);
  gemm_fused2<<<dim3(MPAD / 128, HID / 128), 256, 0, stream>>>(
      XP, W1T, W2F, b1, b2, starts, perm, out);
}

// Round 7
// 200.042 us; speedup vs baseline: 1.3158x; 1.3144x over previous
//
#include <hip/hip_runtime.h>
#include <hip/hip_bf16.h>
#include <stdint.h>

// Problem constants (fixed by reference)
#define T_TASKS 8
#define DM      1024
#define HID     1024
#define NC      100
#define NCP     128
#define BATCH   8192
#define MPAD    9216      // 8192 + 8*128 worst-case 128-aligned padding

typedef __bf16 bf16x8 __attribute__((ext_vector_type(8)));
typedef float  f32x4  __attribute__((ext_vector_type(4)));
typedef unsigned int u32;
#define GAS __attribute__((address_space(1)))
#define LAS __attribute__((address_space(3)))

__device__ __forceinline__ unsigned short f2bf(float f) {
  __hip_bfloat16 h = __float2bfloat16(f);
  return __builtin_bit_cast(unsigned short, h);
}

// ---------------------------------------------------------------------------
// init: zero d_out (atomic target), perm = -1, gmeta = 0.
// ---------------------------------------------------------------------------
__global__ void init_k(float* __restrict__ out, int* __restrict__ perm,
                       int* __restrict__ gmeta) {
  const int gid = blockIdx.x * 256 + threadIdx.x;
  const uint4 z  = {0u, 0u, 0u, 0u};
  const uint4 m1 = {0xFFFFFFFFu, 0xFFFFFFFFu, 0xFFFFFFFFu, 0xFFFFFFFFu};
  uint4* o4 = (uint4*)out;
  for (int i = gid; i < (BATCH * NC) / 4; i += 512 * 256) o4[i] = z;
  uint4* p4 = (uint4*)perm;
  for (int i = gid; i < MPAD / 4; i += 512 * 256) p4[i] = m1;
  if (gid < 16) gmeta[gid] = 0;
}

// ---------------------------------------------------------------------------
// count: per-block LDS histogram -> 8 global atomics. grid 32 x 256.
// ---------------------------------------------------------------------------
__global__ void count_k(const int* __restrict__ task_id, int* __restrict__ gmeta) {
  __shared__ int h[T_TASKS];
  const int tid = threadIdx.x;
  if (tid < T_TASKS) h[tid] = 0;
  __syncthreads();
  atomicAdd(&h[task_id[blockIdx.x * 256 + tid]], 1);
  __syncthreads();
  if (tid < T_TASKS) atomicAdd(&gmeta[tid], h[tid]);
}

// ---------------------------------------------------------------------------
// scatter: starts from complete gcnt; per-block local slots + one global
// range reservation per task per block. grid 32 x 256.
// ---------------------------------------------------------------------------
__global__ void scatter_k(const int* __restrict__ task_id, int* __restrict__ gmeta,
                          int* __restrict__ perm, int* __restrict__ starts) {
  __shared__ int h[T_TASKS];
  __shared__ int base[T_TASKS];
  __shared__ int sst[T_TASKS + 1];
  const int tid = threadIdx.x;
  if (tid < T_TASKS) h[tid] = 0;
  if (tid == 0) {
    int off = 0;
    for (int t = 0; t < T_TASKS; ++t) {
      sst[t] = off;
      off += (gmeta[t] + 127) & ~127;
    }
    sst[T_TASKS] = off;
  }
  __syncthreads();
  const int r = blockIdx.x * 256 + tid;
  const int t = task_id[r];
  const int slot = atomicAdd(&h[t], 1);
  __syncthreads();
  if (tid < T_TASKS) base[tid] = atomicAdd(&gmeta[8 + tid], h[tid]);
  __syncthreads();
  perm[sst[t] + base[t] + slot] = r;
  if (blockIdx.x == 0 && tid <= T_TASKS) starts[tid] = sst[tid];
}

// ---------------------------------------------------------------------------
// gather+convert x rows into permuted bf16 XP (zeros for pads). grid MPAD x 256.
// ---------------------------------------------------------------------------
__global__ void gather_x(const float* __restrict__ x,
                         const int* __restrict__ perm,
                         unsigned short* __restrict__ XP) {
  const int p = blockIdx.x;
  const int r = perm[p];
  const int c = threadIdx.x * 4;
  ushort4 v;
  if (r >= 0) {
    const float4 f = *(const float4*)(x + (size_t)r * DM + c);
    v.x = f2bf(f.x); v.y = f2bf(f.y); v.z = f2bf(f.z); v.w = f2bf(f.w);
  } else {
    v.x = 0; v.y = 0; v.z = 0; v.w = 0;
  }
  *(ushort4*)(XP + (size_t)p * DM + c) = v;
}

// ---------------------------------------------------------------------------
// W1 [t][d][h] fp32 -> W1T [t][h][d] bf16  (LDS-tiled 64x64)
// ---------------------------------------------------------------------------
__global__ void transpose_w1(const float* __restrict__ W1,
                             unsigned short* __restrict__ W1T) {
  __shared__ unsigned short tile[64][65];
  const int t  = blockIdx.z;
  const int d0 = blockIdx.x * 64;
  const int h0 = blockIdx.y * 64;
  const int tid = threadIdx.x;
  const float* src = W1 + (size_t)t * DM * HID;
  unsigned short* dst = W1T + (size_t)t * HID * DM;
#pragma unroll
  for (int i = 0; i < 16; ++i) {
    int idx = tid + 256 * i;
    int ld = idx >> 6, lh = idx & 63;
    tile[lh][ld] = f2bf(src[(size_t)(d0 + ld) * HID + h0 + lh]);
  }
  __syncthreads();
#pragma unroll
  for (int i = 0; i < 16; ++i) {
    int idx = tid + 256 * i;
    int lh = idx >> 6, ld = idx & 63;
    dst[(size_t)(h0 + lh) * DM + d0 + ld] = tile[lh][ld];
  }
}

// ---------------------------------------------------------------------------
// W2 [t][h][c<100] fp32 -> W2F fragment-packed bf16 (c padded to 128).
// frag(t, ci, kc): lane l holds c = ci*16+(l&15), h = kc*32+(l>>4)*8+j.
// grid (16 h-tiles, 8 t) x 256.  (verified correct rounds 5-6)
// ---------------------------------------------------------------------------
__global__ void transpose_w2_packed(const float* __restrict__ W2,
                                    unsigned short* __restrict__ W2F) {
  __shared__ unsigned short tile[128 * 72];
  const int t  = blockIdx.y;
  const int h0 = blockIdx.x * 64;
  const int tid = threadIdx.x;
  const float* src = W2 + (size_t)t * HID * NC;
#pragma unroll
  for (int i = 0; i < 36; ++i) tile[tid + 256 * i] = 0;
  __syncthreads();
#pragma unroll
  for (int i = 0; i < 32; ++i) {
    const int idx = tid + 256 * i;
    const int row = idx >> 7, col = idx & 127;
    if (col < NC)
      tile[col * 72 + row] = f2bf(src[(size_t)(h0 + row) * NC + col]);
  }
  __syncthreads();
  const int w = tid >> 6, lane = tid & 63;
  const int lr = lane & 15, quad = lane >> 4;
#pragma unroll
  for (int e = 0; e < 4; ++e) {
    const int fi = w * 4 + e;
    const int ci = fi >> 1, kcl = fi & 1;
    const uint4 v = *(const uint4*)&tile[(ci * 16 + lr) * 72 + kcl * 32 + quad * 8];
    unsigned short* dst =
        W2F + (((size_t)t * 8 + ci) * 32 + (h0 >> 5) + kcl) * 512 + lane * 8;
    *(uint4*)dst = v;
  }
}

// ---------------------------------------------------------------------------
// Fused MLP GEMM. K-loop is round-2's measured 46.4us core, UNCHANGED:
// 128x128 tile, BK=64, global_load_lds width=16, XOR chunk swizzle on
// unpadded LDS (0 bank conflicts measured), plain __syncthreads.
// grid (72, 8), 256 thr = 4 waves in 2x2; wave = 64x64 = 4x4 MFMA 16x16x32.
// Fused epilogue: h = relu(acc+b1) -> bf16 -> hS (C->A layout, stride 136)
// -> mm2 vs frag-packed W2F k-slice [n0, n0+128) -> unsafeAtomicAdd partial
// scatter to out via perm (+b2 on blockIdx.y==0). No HB, no second GEMM.
// ---------------------------------------------------------------------------
__global__ __launch_bounds__(256, 2) void gemm_fused3(
    const unsigned short* __restrict__ XP,     // [MPAD][1024] bf16 permuted
    const unsigned short* __restrict__ W1T,    // [T][HID][1024] bf16
    const unsigned short* __restrict__ W2F,    // [T][8][32][512] frag-packed
    const float* __restrict__ b1,              // [T][HID]
    const float* __restrict__ b2,              // [T][NC]
    const int* __restrict__ starts,            // [9]
    const int* __restrict__ perm,              // [MPAD]
    float* __restrict__ Out)                   // [BATCH][NC] fp32 (zeroed)
{
  __shared__ __align__(16) unsigned short lds[18432];  // 36,864 B
  unsigned short* As = lds;                    // [128 rows][8 chunks][8 shorts]
  unsigned short* Bs = lds + 8192;             // same
  unsigned short* hS = lds;                    // reuse: [128][136] = 34,816 B

  const int tid = threadIdx.x;
  const int p0  = blockIdx.x * 128;
  const int n0  = blockIdx.y * 128;

  int task = 0;
#pragma unroll
  for (int t = 1; t < T_TASKS; ++t)
    if (p0 >= starts[t]) task = t;

  const int wave = tid >> 6;
  const int lane = tid & 63;
  const int wm   = (wave >> 1) * 64;
  const int wn   = (wave & 1) * 64;
  const int lr   = lane & 15;
  const int quad = lane >> 4;

  // --- staging pointers (R2-verbatim): XOR swizzle, wave-uniform LDS dest ---
  const int crow = tid >> 3;                   // 0..31
  const int kc   = (tid & 7) ^ (crow & 7);
  const unsigned short* pA[4];
  const unsigned short* pB[4];
  const unsigned short* Bg = W1T + ((size_t)task * HID + n0) * 1024;
#pragma unroll
  for (int i = 0; i < 4; ++i) {
    const int row = crow + 32 * i;
    pA[i] = XP + (size_t)(p0 + row) * 1024 + kc * 8;
    pB[i] = Bg + (size_t)row * 1024 + kc * 8;
  }

  f32x4 acc[4][4];
#pragma unroll
  for (int i = 0; i < 4; ++i)
#pragma unroll
    for (int j = 0; j < 4; ++j) acc[i][j] = (f32x4){0.f, 0.f, 0.f, 0.f};

  const int sw0 = quad ^ (lr & 7);             // swizzled chunk col, kk=0
  const int sw1 = (4 + quad) ^ (lr & 7);       // swizzled chunk col, kk=32

  for (int k0 = 0; k0 < 1024; k0 += 64) {
#pragma unroll
    for (int i = 0; i < 4; ++i) {
      __builtin_amdgcn_global_load_lds((const GAS u32*)(pA[i] + k0),
                                       (LAS u32*)&As[(tid + 256 * i) * 8], 16, 0, 0);
      __builtin_amdgcn_global_load_lds((const GAS u32*)(pB[i] + k0),
                                       (LAS u32*)&Bs[(tid + 256 * i) * 8], 16, 0, 0);
    }
    __syncthreads();
    {
      bf16x8 a[4], b[4];
#pragma unroll
      for (int i = 0; i < 4; ++i)
        a[i] = *(const bf16x8*)&As[((wm + i * 16 + lr) * 8 + sw0) * 8];
#pragma unroll
      for (int j = 0; j < 4; ++j)
        b[j] = *(const bf16x8*)&Bs[((wn + j * 16 + lr) * 8 + sw0) * 8];
#pragma unroll
      for (int i = 0; i < 4; ++i)
#pragma unroll
        for (int j = 0; j < 4; ++j)
          acc[i][j] = __builtin_amdgcn_mfma_f32_16x16x32_bf16(a[i], b[j], acc[i][j], 0, 0, 0);
#pragma unroll
      for (int i = 0; i < 4; ++i)
        a[i] = *(const bf16x8*)&As[((wm + i * 16 + lr) * 8 + sw1) * 8];
#pragma unroll
      for (int j = 0; j < 4; ++j)
        b[j] = *(const bf16x8*)&Bs[((wn + j * 16 + lr) * 8 + sw1) * 8];
#pragma unroll
      for (int i = 0; i < 4; ++i)
#pragma unroll
        for (int j = 0; j < 4; ++j)
          acc[i][j] = __builtin_amdgcn_mfma_f32_16x16x32_bf16(a[i], b[j], acc[i][j], 0, 0, 0);
    }
    __syncthreads();
  }

  // --- h = relu(acc + b1) -> bf16 -> hS (C-layout in, A-layout rows) ---
  // C/D layout: col = lane&15, row = quad*4 + reg  [m89]
  float b1v[4];
#pragma unroll
  for (int ni = 0; ni < 4; ++ni)
    b1v[ni] = b1[task * HID + n0 + wn + ni * 16 + lr];
#pragma unroll
  for (int mi = 0; mi < 4; ++mi)
#pragma unroll
    for (int r = 0; r < 4; ++r) {
      const int row = wm + mi * 16 + quad * 4 + r;
#pragma unroll
      for (int ni = 0; ni < 4; ++ni) {
        float v = acc[mi][ni][r] + b1v[ni];
        v = v > 0.f ? v : 0.f;
        hS[row * 136 + wn + ni * 16 + lr] = f2bf(v);
      }
    }
  __syncthreads();

  // --- mm2: h[128][128-slice] x W2 k-slice -> 128x128 partial logits ---
  // wave: rows [wm,wm+64) x classes [wn,wn+64); W2F kc range = by*4 + e.
  const int cbase = (wave & 1) * 4;
  const unsigned short* pW2 =
      W2F + (((size_t)task * 8 + cbase) * 32 + blockIdx.y * 4) * 512 + lane * 8;

  f32x4 acc2[4][4];
#pragma unroll
  for (int mi = 0; mi < 4; ++mi)
#pragma unroll
    for (int ci = 0; ci < 4; ++ci) acc2[mi][ci] = (f32x4){0.f, 0.f, 0.f, 0.f};

#pragma unroll
  for (int e = 0; e < 4; ++e) {
    bf16x8 w2p[4], a2[4];
#pragma unroll
    for (int ci = 0; ci < 4; ++ci)
      w2p[ci] = *(const bf16x8*)(pW2 + ((size_t)ci * 32 + e) * 512);
#pragma unroll
    for (int mi = 0; mi < 4; ++mi)
      a2[mi] = *(const bf16x8*)&hS[(wm + mi * 16 + lr) * 136 + e * 32 + quad * 8];
#pragma unroll
    for (int mi = 0; mi < 4; ++mi)
#pragma unroll
      for (int ci = 0; ci < 4; ++ci)
        acc2[mi][ci] = __builtin_amdgcn_mfma_f32_16x16x32_bf16(
            a2[mi], w2p[ci], acc2[mi][ci], 0, 0, 0);
  }

  // --- atomic partial scatter to out; +b2 once (blockIdx.y==0) ---
  const float* bv2 = b2 + (size_t)task * NC;
  const bool addb = (blockIdx.y == 0);
#pragma unroll
  for (int mi = 0; mi < 4; ++mi)
#pragma unroll
    for (int r = 0; r < 4; ++r) {
      const int og = perm[p0 + wm + mi * 16 + quad * 4 + r];
      if (og < 0) continue;
#pragma unroll
      for (int ci = 0; ci < 4; ++ci) {
        const int col = wn + ci * 16 + lr;
        if (col < NC) {
          float v = acc2[mi][ci][r];
          if (addb) v += bv2[col];
          unsafeAtomicAdd(&Out[(size_t)og * NC + col], v);
        }
      }
    }
}

// ---------------------------------------------------------------------------
// Workspace layout (bytes):
//   perm   int[9216]            @ 0           (36864)
//   gmeta  int[16]              @ 36864
//   starts int[9]               @ 36928
//   XP     bf16[9216*1024]      @ 65536       (18874368)
//   W1T    bf16[8*1024*1024]    @ 18939904    (16777216)
//   W2F    bf16[8*8*32*512]     @ 35717120    (2097152)   end 37814272
// ---------------------------------------------------------------------------
extern "C" void kernel_launch(void* const* d_in, const int* in_sizes, int n_in,
                              void* d_out, int out_size, void* d_ws, size_t ws_size,
                              hipStream_t stream) {
  const float* x       = (const float*)d_in[0];
  const int*   task_id = (const int*)d_in[1];
  const float* W1      = (const float*)d_in[2];
  const float* b1      = (const float*)d_in[3];
  const float* W2      = (const float*)d_in[4];
  const float* b2      = (const float*)d_in[5];
  float* out = (float*)d_out;

  char* ws = (char*)d_ws;
  int* perm   = (int*)(ws + 0);
  int* gmeta  = (int*)(ws + 36864);
  int* starts = (int*)(ws + 36928);
  unsigned short* XP  = (unsigned short*)(ws + 65536);
  unsigned short* W1T = (unsigned short*)(ws + 18939904);
  unsigned short* W2F = (unsigned short*)(ws + 35717120);

  init_k<<<512, 256, 0, stream>>>(out, perm, gmeta);
  count_k<<<32, 256, 0, stream>>>(task_id, gmeta);
  scatter_k<<<32, 256, 0, stream>>>(task_id, gmeta, perm, starts);
  gather_x<<<MPAD, 256, 0, stream>>>(x, perm, XP);
  transpose_w1<<<dim3(16, 16, T_TASKS), 256, 0, stream>>>(W1, W1T);
  transpose_w2_packed<<<dim3(16, T_TASKS), 256, 0, stream>>>(W2, W2F);
  gemm_fused3<<<dim3(MPAD / 128, HID / 128), 256, 0, stream>>>(
      XP, W1T, W2F, b1, b2, starts, perm, out);
}

// Round 8
// 160.381 us; speedup vs baseline: 1.6412x; 1.2473x over previous
//
#include <hip/hip_runtime.h>
#include <hip/hip_bf16.h>
#include <stdint.h>

// Problem constants (fixed by reference)
#define T_TASKS 8
#define DM      1024
#define HID     1024
#define NC      100
#define NCP     128
#define BATCH   8192
#define MPAD    9216      // 8192 + 8*128 worst-case 128-aligned padding

typedef __bf16 bf16x8 __attribute__((ext_vector_type(8)));
typedef float  f32x4  __attribute__((ext_vector_type(4)));
typedef unsigned int u32;
#define GAS __attribute__((address_space(1)))
#define LAS __attribute__((address_space(3)))

__device__ __forceinline__ unsigned short f2bf(float f) {
  __hip_bfloat16 h = __float2bfloat16(f);
  return __builtin_bit_cast(unsigned short, h);
}

__device__ __forceinline__ float bf2f(unsigned short u) {
  const u32 v = ((u32)u) << 16;
  return __builtin_bit_cast(float, v);
}

// ---------------------------------------------------------------------------
// init: perm = -1, gmeta = 0.  (out no longer zeroed: reduce_k writes all of
// it directly.)
// ---------------------------------------------------------------------------
__global__ void init_k(int* __restrict__ perm, int* __restrict__ gmeta) {
  const int gid = blockIdx.x * 256 + threadIdx.x;
  const uint4 m1 = {0xFFFFFFFFu, 0xFFFFFFFFu, 0xFFFFFFFFu, 0xFFFFFFFFu};
  uint4* p4 = (uint4*)perm;
  if (gid < MPAD / 4) p4[gid] = m1;
  if (gid < 16) gmeta[gid] = 0;
}

// ---------------------------------------------------------------------------
// count: per-block LDS histogram -> 8 global atomics. grid 32 x 256.
// ---------------------------------------------------------------------------
__global__ void count_k(const int* __restrict__ task_id, int* __restrict__ gmeta) {
  __shared__ int h[T_TASKS];
  const int tid = threadIdx.x;
  if (tid < T_TASKS) h[tid] = 0;
  __syncthreads();
  atomicAdd(&h[task_id[blockIdx.x * 256 + tid]], 1);
  __syncthreads();
  if (tid < T_TASKS) atomicAdd(&gmeta[tid], h[tid]);
}

// ---------------------------------------------------------------------------
// scatter: starts from complete gcnt; per-block local slots + one global
// range reservation per task per block. grid 32 x 256.
// ---------------------------------------------------------------------------
__global__ void scatter_k(const int* __restrict__ task_id, int* __restrict__ gmeta,
                          int* __restrict__ perm, int* __restrict__ starts) {
  __shared__ int h[T_TASKS];
  __shared__ int base[T_TASKS];
  __shared__ int sst[T_TASKS + 1];
  const int tid = threadIdx.x;
  if (tid < T_TASKS) h[tid] = 0;
  if (tid == 0) {
    int off = 0;
    for (int t = 0; t < T_TASKS; ++t) {
      sst[t] = off;
      off += (gmeta[t] + 127) & ~127;
    }
    sst[T_TASKS] = off;
  }
  __syncthreads();
  const int r = blockIdx.x * 256 + tid;
  const int t = task_id[r];
  const int slot = atomicAdd(&h[t], 1);
  __syncthreads();
  if (tid < T_TASKS) base[tid] = atomicAdd(&gmeta[8 + tid], h[tid]);
  __syncthreads();
  perm[sst[t] + base[t] + slot] = r;
  if (blockIdx.x == 0 && tid <= T_TASKS) starts[tid] = sst[tid];
}

// ---------------------------------------------------------------------------
// gather+convert x rows into permuted bf16 XP (zeros for pads). grid MPAD x 256.
// ---------------------------------------------------------------------------
__global__ void gather_x(const float* __restrict__ x,
                         const int* __restrict__ perm,
                         unsigned short* __restrict__ XP) {
  const int p = blockIdx.x;
  const int r = perm[p];
  const int c = threadIdx.x * 4;
  ushort4 v;
  if (r >= 0) {
    const float4 f = *(const float4*)(x + (size_t)r * DM + c);
    v.x = f2bf(f.x); v.y = f2bf(f.y); v.z = f2bf(f.z); v.w = f2bf(f.w);
  } else {
    v.x = 0; v.y = 0; v.z = 0; v.w = 0;
  }
  *(ushort4*)(XP + (size_t)p * DM + c) = v;
}

// ---------------------------------------------------------------------------
// W1 [t][d][h] fp32 -> W1T [t][h][d] bf16  (LDS-tiled 64x64)
// ---------------------------------------------------------------------------
__global__ void transpose_w1(const float* __restrict__ W1,
                             unsigned short* __restrict__ W1T) {
  __shared__ unsigned short tile[64][65];
  const int t  = blockIdx.z;
  const int d0 = blockIdx.x * 64;
  const int h0 = blockIdx.y * 64;
  const int tid = threadIdx.x;
  const float* src = W1 + (size_t)t * DM * HID;
  unsigned short* dst = W1T + (size_t)t * HID * DM;
#pragma unroll
  for (int i = 0; i < 16; ++i) {
    int idx = tid + 256 * i;
    int ld = idx >> 6, lh = idx & 63;
    tile[lh][ld] = f2bf(src[(size_t)(d0 + ld) * HID + h0 + lh]);
  }
  __syncthreads();
#pragma unroll
  for (int i = 0; i < 16; ++i) {
    int idx = tid + 256 * i;
    int lh = idx >> 6, ld = idx & 63;
    dst[(size_t)(h0 + lh) * DM + d0 + ld] = tile[lh][ld];
  }
}

// ---------------------------------------------------------------------------
// W2 [t][h][c<100] fp32 -> W2F fragment-packed bf16 (c padded to 128).
// frag(t, ci, kc): lane l holds c = ci*16+(l&15), h = kc*32+(l>>4)*8+j.
// grid (16 h-tiles, 8 t) x 256.  (verified correct rounds 5-7)
// ---------------------------------------------------------------------------
__global__ void transpose_w2_packed(const float* __restrict__ W2,
                                    unsigned short* __restrict__ W2F) {
  __shared__ unsigned short tile[128 * 72];
  const int t  = blockIdx.y;
  const int h0 = blockIdx.x * 64;
  const int tid = threadIdx.x;
  const float* src = W2 + (size_t)t * HID * NC;
#pragma unroll
  for (int i = 0; i < 36; ++i) tile[tid + 256 * i] = 0;
  __syncthreads();
#pragma unroll
  for (int i = 0; i < 32; ++i) {
    const int idx = tid + 256 * i;
    const int row = idx >> 7, col = idx & 127;
    if (col < NC)
      tile[col * 72 + row] = f2bf(src[(size_t)(h0 + row) * NC + col]);
  }
  __syncthreads();
  const int w = tid >> 6, lane = tid & 63;
  const int lr = lane & 15, quad = lane >> 4;
#pragma unroll
  for (int e = 0; e < 4; ++e) {
    const int fi = w * 4 + e;
    const int ci = fi >> 1, kcl = fi & 1;
    const uint4 v = *(const uint4*)&tile[(ci * 16 + lr) * 72 + kcl * 32 + quad * 8];
    unsigned short* dst =
        W2F + (((size_t)t * 8 + ci) * 32 + (h0 >> 5) + kcl) * 512 + lane * 8;
    *(uint4*)dst = v;
  }
}

// ---------------------------------------------------------------------------
// Fused MLP GEMM (R7 structure; R2-measured K-loop UNCHANGED). grid (72, 8).
// Epilogue change vs R7: NO atomics. Partial logits (this block's K-slice of
// mm2) are stored as bf16 to Lp[by][prow][128] with plain coalesced stores;
// reduce_k combines the 8 slices. Blocks fully past the real row count
// (starts[8]) exit early; reduce_k skips those rows via perm<0.
// ---------------------------------------------------------------------------
__global__ __launch_bounds__(256, 2) void gemm_fused4(
    const unsigned short* __restrict__ XP,     // [MPAD][1024] bf16 permuted
    const unsigned short* __restrict__ W1T,    // [T][HID][1024] bf16
    const unsigned short* __restrict__ W2F,    // [T][8][32][512] frag-packed
    const float* __restrict__ b1,              // [T][HID]
    const int* __restrict__ starts,            // [9]
    unsigned short* __restrict__ Lp)           // [8][MPAD][128] bf16 partials
{
  __shared__ __align__(16) unsigned short lds[18432];  // 36,864 B
  unsigned short* As = lds;                    // [128 rows][8 chunks][8 shorts]
  unsigned short* Bs = lds + 8192;             // same
  unsigned short* hS = lds;                    // reuse: [128][136] = 34,816 B

  const int tid = threadIdx.x;
  const int p0  = blockIdx.x * 128;
  const int n0  = blockIdx.y * 128;

  if (p0 >= starts[T_TASKS]) return;           // all-pad tail tile: skip

  int task = 0;
#pragma unroll
  for (int t = 1; t < T_TASKS; ++t)
    if (p0 >= starts[t]) task = t;

  const int wave = tid >> 6;
  const int lane = tid & 63;
  const int wm   = (wave >> 1) * 64;
  const int wn   = (wave & 1) * 64;
  const int lr   = lane & 15;
  const int quad = lane >> 4;

  // --- staging pointers (R2-verbatim): XOR swizzle, wave-uniform LDS dest ---
  const int crow = tid >> 3;                   // 0..31
  const int kc   = (tid & 7) ^ (crow & 7);
  const unsigned short* pA[4];
  const unsigned short* pB[4];
  const unsigned short* Bg = W1T + ((size_t)task * HID + n0) * 1024;
#pragma unroll
  for (int i = 0; i < 4; ++i) {
    const int row = crow + 32 * i;
    pA[i] = XP + (size_t)(p0 + row) * 1024 + kc * 8;
    pB[i] = Bg + (size_t)row * 1024 + kc * 8;
  }

  f32x4 acc[4][4];
#pragma unroll
  for (int i = 0; i < 4; ++i)
#pragma unroll
    for (int j = 0; j < 4; ++j) acc[i][j] = (f32x4){0.f, 0.f, 0.f, 0.f};

  const int sw0 = quad ^ (lr & 7);             // swizzled chunk col, kk=0
  const int sw1 = (4 + quad) ^ (lr & 7);       // swizzled chunk col, kk=32

  for (int k0 = 0; k0 < 1024; k0 += 64) {
#pragma unroll
    for (int i = 0; i < 4; ++i) {
      __builtin_amdgcn_global_load_lds((const GAS u32*)(pA[i] + k0),
                                       (LAS u32*)&As[(tid + 256 * i) * 8], 16, 0, 0);
      __builtin_amdgcn_global_load_lds((const GAS u32*)(pB[i] + k0),
                                       (LAS u32*)&Bs[(tid + 256 * i) * 8], 16, 0, 0);
    }
    __syncthreads();
    {
      bf16x8 a[4], b[4];
#pragma unroll
      for (int i = 0; i < 4; ++i)
        a[i] = *(const bf16x8*)&As[((wm + i * 16 + lr) * 8 + sw0) * 8];
#pragma unroll
      for (int j = 0; j < 4; ++j)
        b[j] = *(const bf16x8*)&Bs[((wn + j * 16 + lr) * 8 + sw0) * 8];
#pragma unroll
      for (int i = 0; i < 4; ++i)
#pragma unroll
        for (int j = 0; j < 4; ++j)
          acc[i][j] = __builtin_amdgcn_mfma_f32_16x16x32_bf16(a[i], b[j], acc[i][j], 0, 0, 0);
#pragma unroll
      for (int i = 0; i < 4; ++i)
        a[i] = *(const bf16x8*)&As[((wm + i * 16 + lr) * 8 + sw1) * 8];
#pragma unroll
      for (int j = 0; j < 4; ++j)
        b[j] = *(const bf16x8*)&Bs[((wn + j * 16 + lr) * 8 + sw1) * 8];
#pragma unroll
      for (int i = 0; i < 4; ++i)
#pragma unroll
        for (int j = 0; j < 4; ++j)
          acc[i][j] = __builtin_amdgcn_mfma_f32_16x16x32_bf16(a[i], b[j], acc[i][j], 0, 0, 0);
    }
    __syncthreads();
  }

  // --- h = relu(acc + b1) -> bf16 -> hS (C-layout in, A-layout rows) ---
  float b1v[4];
#pragma unroll
  for (int ni = 0; ni < 4; ++ni)
    b1v[ni] = b1[task * HID + n0 + wn + ni * 16 + lr];
#pragma unroll
  for (int mi = 0; mi < 4; ++mi)
#pragma unroll
    for (int r = 0; r < 4; ++r) {
      const int row = wm + mi * 16 + quad * 4 + r;
#pragma unroll
      for (int ni = 0; ni < 4; ++ni) {
        float v = acc[mi][ni][r] + b1v[ni];
        v = v > 0.f ? v : 0.f;
        hS[row * 136 + wn + ni * 16 + lr] = f2bf(v);
      }
    }
  __syncthreads();

  // --- mm2: h[128][128-slice] x W2 k-slice -> 128x128 partial logits ---
  const int cbase = (wave & 1) * 4;
  const unsigned short* pW2 =
      W2F + (((size_t)task * 8 + cbase) * 32 + blockIdx.y * 4) * 512 + lane * 8;

  f32x4 acc2[4][4];
#pragma unroll
  for (int mi = 0; mi < 4; ++mi)
#pragma unroll
    for (int ci = 0; ci < 4; ++ci) acc2[mi][ci] = (f32x4){0.f, 0.f, 0.f, 0.f};

#pragma unroll
  for (int e = 0; e < 4; ++e) {
    bf16x8 w2p[4], a2[4];
#pragma unroll
    for (int ci = 0; ci < 4; ++ci)
      w2p[ci] = *(const bf16x8*)(pW2 + ((size_t)ci * 32 + e) * 512);
#pragma unroll
    for (int mi = 0; mi < 4; ++mi)
      a2[mi] = *(const bf16x8*)&hS[(wm + mi * 16 + lr) * 136 + e * 32 + quad * 8];
#pragma unroll
    for (int mi = 0; mi < 4; ++mi)
#pragma unroll
      for (int ci = 0; ci < 4; ++ci)
        acc2[mi][ci] = __builtin_amdgcn_mfma_f32_16x16x32_bf16(
            a2[mi], w2p[ci], acc2[mi][ci], 0, 0, 0);
  }

  // --- store bf16 partials, plain coalesced (no atomics) ---
  unsigned short* lp = Lp + ((size_t)blockIdx.y * MPAD + p0) * NCP;
#pragma unroll
  for (int mi = 0; mi < 4; ++mi)
#pragma unroll
    for (int r = 0; r < 4; ++r) {
      const int row = wm + mi * 16 + quad * 4 + r;
#pragma unroll
      for (int ci = 0; ci < 4; ++ci)
        lp[row * NCP + wn + ci * 16 + lr] = f2bf(acc2[mi][ci][r]);
    }
}

// ---------------------------------------------------------------------------
// reduce: sum 8 bf16 partial slices, +b2, scatter to out via perm.
// grid 1152 x 256; thread -> (row = gid>>5, c4 = (gid&31)*4). Rows with
// perm<0 (pads / unwritten tail) skipped. Covers every (orig,row col<100).
// ---------------------------------------------------------------------------
__global__ void reduce_k(const unsigned short* __restrict__ Lp,
                         const int* __restrict__ perm,
                         const int* __restrict__ task_id,
                         const float* __restrict__ b2,
                         float* __restrict__ Out) {
  const int gid = blockIdx.x * 256 + threadIdx.x;
  const int row = gid >> 5;
  const int c4  = (gid & 31) * 4;
  if (c4 >= NC) return;
  const int og = perm[row];
  if (og < 0) return;
  float s0 = 0.f, s1 = 0.f, s2 = 0.f, s3 = 0.f;
#pragma unroll
  for (int sp = 0; sp < 8; ++sp) {
    const ushort4 v = *(const ushort4*)(Lp + ((size_t)sp * MPAD + row) * NCP + c4);
    s0 += bf2f(v.x); s1 += bf2f(v.y); s2 += bf2f(v.z); s3 += bf2f(v.w);
  }
  const int task = task_id[og];
  const float4 bb = *(const float4*)(b2 + (size_t)task * NC + c4);
  float4 o;
  o.x = s0 + bb.x; o.y = s1 + bb.y; o.z = s2 + bb.z; o.w = s3 + bb.w;
  *(float4*)(Out + (size_t)og * NC + c4) = o;
}

// ---------------------------------------------------------------------------
// Workspace layout (bytes) — total 56,688,640 (same as round-1 proven size):
//   perm   int[9216]            @ 0           (36864)
//   gmeta  int[16]              @ 36864
//   starts int[9]               @ 36928
//   XP     bf16[9216*1024]      @ 65536       (18874368)
//   W1T    bf16[8*1024*1024]    @ 18939904    (16777216)
//   W2F    bf16[8*8*32*512]     @ 35717120    (2097152)
//   Lp     bf16[8*9216*128]     @ 37814272    (18874368)  end 56688640
// ---------------------------------------------------------------------------
extern "C" void kernel_launch(void* const* d_in, const int* in_sizes, int n_in,
                              void* d_out, int out_size, void* d_ws, size_t ws_size,
                              hipStream_t stream) {
  const float* x       = (const float*)d_in[0];
  const int*   task_id = (const int*)d_in[1];
  const float* W1      = (const float*)d_in[2];
  const float* b1      = (const float*)d_in[3];
  const float* W2      = (const float*)d_in[4];
  const float* b2      = (const float*)d_in[5];
  float* out = (float*)d_out;

  char* ws = (char*)d_ws;
  int* perm   = (int*)(ws + 0);
  int* gmeta  = (int*)(ws + 36864);
  int* starts = (int*)(ws + 36928);
  unsigned short* XP  = (unsigned short*)(ws + 65536);
  unsigned short* W1T = (unsigned short*)(ws + 18939904);
  unsigned short* W2F = (unsigned short*)(ws + 35717120);
  unsigned short* Lp  = (unsigned short*)(ws + 37814272);

  init_k<<<9, 256, 0, stream>>>(perm, gmeta);
  count_k<<<32, 256, 0, stream>>>(task_id, gmeta);
  scatter_k<<<32, 256, 0, stream>>>(task_id, gmeta, perm, starts);
  gather_x<<<MPAD, 256, 0, stream>>>(x, perm, XP);
  transpose_w1<<<dim3(16, 16, T_TASKS), 256, 0, stream>>>(W1, W1T);
  transpose_w2_packed<<<dim3(16, T_TASKS), 256, 0, stream>>>(W2, W2F);
  gemm_fused4<<<dim3(MPAD / 128, HID / 128), 256, 0, stream>>>(
      XP, W1T, W2F, b1, starts, Lp);
  reduce_k<<<MPAD * 32 / 256, 256, 0, stream>>>(Lp, perm, task_id, b2, out);
}

// Round 9
// 153.287 us; speedup vs baseline: 1.7172x; 1.0463x over previous
//
#include <hip/hip_runtime.h>
#include <hip/hip_bf16.h>
#include <stdint.h>

// Problem constants (fixed by reference)
#define T_TASKS 8
#define DM      1024
#define HID     1024
#define NC      100
#define NCP     128
#define BATCH   8192
#define MPAD    9216      // 8192 + 8*128 worst-case 128-aligned padding

typedef __bf16 bf16x8 __attribute__((ext_vector_type(8)));
typedef float  f32x4  __attribute__((ext_vector_type(4)));
typedef unsigned int u32;
#define GAS __attribute__((address_space(1)))
#define LAS __attribute__((address_space(3)))

__device__ __forceinline__ unsigned short f2bf(float f) {
  __hip_bfloat16 h = __float2bfloat16(f);
  return __builtin_bit_cast(unsigned short, h);
}

__device__ __forceinline__ float bf2f(unsigned short u) {
  const u32 v = ((u32)u) << 16;
  return __builtin_bit_cast(float, v);
}

// ---------------------------------------------------------------------------
// count: per-block LDS histogram -> gcount[b][t] (no atomics, no init pass).
// Also clears its stripe of perm to -1. grid 32 x 256.
// ---------------------------------------------------------------------------
__global__ void count_k(const int* __restrict__ task_id,
                        int* __restrict__ gcount, int* __restrict__ perm) {
  __shared__ int h[T_TASKS];
  const int tid = threadIdx.x;
  const int bx  = blockIdx.x;
  if (tid < T_TASKS) h[tid] = 0;
  __syncthreads();
  atomicAdd(&h[task_id[bx * 256 + tid]], 1);
  const int base = bx * (MPAD / 32);           // 288 per block
  for (int i = tid; i < MPAD / 32; i += 256) perm[base + i] = -1;
  __syncthreads();
  if (tid < T_TASKS) gcount[bx * T_TASKS + tid] = h[tid];
}

// ---------------------------------------------------------------------------
// scatter: each block computes totals + its own prefix from gcount (1024 B),
// then scatters its 256 rows. grid 32 x 256.
// ---------------------------------------------------------------------------
__global__ void scatter_k(const int* __restrict__ task_id,
                          const int* __restrict__ gcount,
                          int* __restrict__ perm, int* __restrict__ starts) {
  __shared__ int h[T_TASKS];
  __shared__ int tot[T_TASKS], prev[T_TASKS];
  __shared__ int sst[T_TASKS + 1];
  const int tid = threadIdx.x;
  const int bx  = blockIdx.x;
  if (tid < T_TASKS) {
    h[tid] = 0;
    int s = 0, p = 0;
    for (int b = 0; b < 32; ++b) {
      const int c = gcount[b * T_TASKS + tid];
      s += c;
      if (b < bx) p += c;
    }
    tot[tid] = s; prev[tid] = p;
  }
  __syncthreads();
  if (tid == 0) {
    int off = 0;
    for (int t = 0; t < T_TASKS; ++t) { sst[t] = off; off += (tot[t] + 127) & ~127; }
    sst[T_TASKS] = off;
  }
  const int r = bx * 256 + tid;
  const int t = task_id[r];
  const int slot = atomicAdd(&h[t], 1);
  __syncthreads();
  perm[sst[t] + prev[t] + slot] = r;
  if (bx == 0 && tid <= T_TASKS) starts[tid] = sst[tid];
}

// ---------------------------------------------------------------------------
// preproc_fused: one launch, three block roles.
//  [0, 9216)          : gather+convert x rows -> permuted bf16 XP (pads=0)
//  [9216, 9216+2048)  : W1 [t][d][h] fp32 -> W1T [t][h][d] bf16 (vectorized:
//                       float4 global loads, ushort8 global stores)
//  [11264, 11392)     : W2 -> W2F fragment-packed bf16 (verified r5-r8)
// ---------------------------------------------------------------------------
#define GX_BLKS MPAD
#define W1_BLKS (T_TASKS * 16 * 16)
#define W2_BLKS (16 * T_TASKS)
__global__ void preproc_fused(const float* __restrict__ x,
                              const int* __restrict__ perm,
                              unsigned short* __restrict__ XP,
                              const float* __restrict__ W1,
                              unsigned short* __restrict__ W1T,
                              const float* __restrict__ W2,
                              unsigned short* __restrict__ W2F) {
  __shared__ unsigned short tile[128 * 72];    // 18,432 B (max of roles)
  const int bid = blockIdx.x;
  const int tid = threadIdx.x;

  if (bid < GX_BLKS) {
    // ---- gather + convert x ----
    const int r = perm[bid];
    const int c = tid * 4;
    ushort4 v;
    if (r >= 0) {
      const float4 f = *(const float4*)(x + (size_t)r * DM + c);
      v.x = f2bf(f.x); v.y = f2bf(f.y); v.z = f2bf(f.z); v.w = f2bf(f.w);
    } else {
      v.x = 0; v.y = 0; v.z = 0; v.w = 0;
    }
    *(ushort4*)(XP + (size_t)bid * DM + c) = v;
    return;
  }

  if (bid < GX_BLKS + W1_BLKS) {
    // ---- W1 transpose, vectorized global sides ----
    const int b  = bid - GX_BLKS;
    const int t  = b >> 8;
    const int rem = b & 255;
    const int d0 = (rem >> 4) * 64;
    const int h0 = (rem & 15) * 64;
    const float* src = W1 + (size_t)t * DM * HID;
    unsigned short* dst = W1T + (size_t)t * HID * DM;
    // phase 1: float4 loads over h; scalar u16 LDS stores into tile[h][d]
#pragma unroll
    for (int i = 0; i < 4; ++i) {
      const int idx = tid + 256 * i;           // 1024 float4 = 64d x 16 chunks
      const int d  = idx >> 4;
      const int hc = (idx & 15) * 4;
      const float4 f = *(const float4*)(src + (size_t)(d0 + d) * HID + h0 + hc);
      tile[(hc + 0) * 65 + d] = f2bf(f.x);
      tile[(hc + 1) * 65 + d] = f2bf(f.y);
      tile[(hc + 2) * 65 + d] = f2bf(f.z);
      tile[(hc + 3) * 65 + d] = f2bf(f.w);
    }
    __syncthreads();
    // phase 2: scalar u16 LDS reads; ushort8 (16B) global stores
#pragma unroll
    for (int i = 0; i < 2; ++i) {
      const int idx = tid + 256 * i;           // 512 ushort8 = 64h x 8 chunks
      const int lh  = idx >> 3;
      const int ldc = idx & 7;
      union { uint4 v; unsigned short s[8]; } o;
#pragma unroll
      for (int q = 0; q < 8; ++q) o.s[q] = tile[lh * 65 + ldc * 8 + q];
      *(uint4*)(dst + (size_t)(h0 + lh) * DM + d0 + ldc * 8) = o.v;
    }
    return;
  }

  // ---- W2 -> frag-packed W2F ----
  {
    const int b  = bid - (GX_BLKS + W1_BLKS);
    const int t  = b >> 4;
    const int h0 = (b & 15) * 64;
    const float* src = W2 + (size_t)t * HID * NC;
#pragma unroll
    for (int i = 0; i < 36; ++i) tile[tid + 256 * i] = 0;
    __syncthreads();
#pragma unroll
    for (int i = 0; i < 32; ++i) {
      const int idx = tid + 256 * i;
      const int row = idx >> 7, col = idx & 127;
      if (col < NC)
        tile[col * 72 + row] = f2bf(src[(size_t)(h0 + row) * NC + col]);
    }
    __syncthreads();
    const int w = tid >> 6, lane = tid & 63;
    const int lr = lane & 15, quad = lane >> 4;
#pragma unroll
    for (int e = 0; e < 4; ++e) {
      const int fi = w * 4 + e;
      const int ci = fi >> 1, kcl = fi & 1;
      const uint4 v = *(const uint4*)&tile[(ci * 16 + lr) * 72 + kcl * 32 + quad * 8];
      unsigned short* dstp =
          W2F + (((size_t)t * 8 + ci) * 32 + (h0 >> 5) + kcl) * 512 + lane * 8;
      *(uint4*)dstp = v;
    }
  }
}

// ---------------------------------------------------------------------------
// Fused MLP GEMM — UNCHANGED from round 8 (proven ~39us, no atomics).
// ---------------------------------------------------------------------------
__global__ __launch_bounds__(256, 2) void gemm_fused4(
    const unsigned short* __restrict__ XP,     // [MPAD][1024] bf16 permuted
    const unsigned short* __restrict__ W1T,    // [T][HID][1024] bf16
    const unsigned short* __restrict__ W2F,    // [T][8][32][512] frag-packed
    const float* __restrict__ b1,              // [T][HID]
    const int* __restrict__ starts,            // [9]
    unsigned short* __restrict__ Lp)           // [8][MPAD][128] bf16 partials
{
  __shared__ __align__(16) unsigned short lds[18432];  // 36,864 B
  unsigned short* As = lds;
  unsigned short* Bs = lds + 8192;
  unsigned short* hS = lds;                    // reuse: [128][136]

  const int tid = threadIdx.x;
  const int p0  = blockIdx.x * 128;
  const int n0  = blockIdx.y * 128;

  if (p0 >= starts[T_TASKS]) return;

  int task = 0;
#pragma unroll
  for (int t = 1; t < T_TASKS; ++t)
    if (p0 >= starts[t]) task = t;

  const int wave = tid >> 6;
  const int lane = tid & 63;
  const int wm   = (wave >> 1) * 64;
  const int wn   = (wave & 1) * 64;
  const int lr   = lane & 15;
  const int quad = lane >> 4;

  const int crow = tid >> 3;
  const int kc   = (tid & 7) ^ (crow & 7);
  const unsigned short* pA[4];
  const unsigned short* pB[4];
  const unsigned short* Bg = W1T + ((size_t)task * HID + n0) * 1024;
#pragma unroll
  for (int i = 0; i < 4; ++i) {
    const int row = crow + 32 * i;
    pA[i] = XP + (size_t)(p0 + row) * 1024 + kc * 8;
    pB[i] = Bg + (size_t)row * 1024 + kc * 8;
  }

  f32x4 acc[4][4];
#pragma unroll
  for (int i = 0; i < 4; ++i)
#pragma unroll
    for (int j = 0; j < 4; ++j) acc[i][j] = (f32x4){0.f, 0.f, 0.f, 0.f};

  const int sw0 = quad ^ (lr & 7);
  const int sw1 = (4 + quad) ^ (lr & 7);

  for (int k0 = 0; k0 < 1024; k0 += 64) {
#pragma unroll
    for (int i = 0; i < 4; ++i) {
      __builtin_amdgcn_global_load_lds((const GAS u32*)(pA[i] + k0),
                                       (LAS u32*)&As[(tid + 256 * i) * 8], 16, 0, 0);
      __builtin_amdgcn_global_load_lds((const GAS u32*)(pB[i] + k0),
                                       (LAS u32*)&Bs[(tid + 256 * i) * 8], 16, 0, 0);
    }
    __syncthreads();
    {
      bf16x8 a[4], b[4];
#pragma unroll
      for (int i = 0; i < 4; ++i)
        a[i] = *(const bf16x8*)&As[((wm + i * 16 + lr) * 8 + sw0) * 8];
#pragma unroll
      for (int j = 0; j < 4; ++j)
        b[j] = *(const bf16x8*)&Bs[((wn + j * 16 + lr) * 8 + sw0) * 8];
#pragma unroll
      for (int i = 0; i < 4; ++i)
#pragma unroll
        for (int j = 0; j < 4; ++j)
          acc[i][j] = __builtin_amdgcn_mfma_f32_16x16x32_bf16(a[i], b[j], acc[i][j], 0, 0, 0);
#pragma unroll
      for (int i = 0; i < 4; ++i)
        a[i] = *(const bf16x8*)&As[((wm + i * 16 + lr) * 8 + sw1) * 8];
#pragma unroll
      for (int j = 0; j < 4; ++j)
        b[j] = *(const bf16x8*)&Bs[((wn + j * 16 + lr) * 8 + sw1) * 8];
#pragma unroll
      for (int i = 0; i < 4; ++i)
#pragma unroll
        for (int j = 0; j < 4; ++j)
          acc[i][j] = __builtin_amdgcn_mfma_f32_16x16x32_bf16(a[i], b[j], acc[i][j], 0, 0, 0);
    }
    __syncthreads();
  }

  float b1v[4];
#pragma unroll
  for (int ni = 0; ni < 4; ++ni)
    b1v[ni] = b1[task * HID + n0 + wn + ni * 16 + lr];
#pragma unroll
  for (int mi = 0; mi < 4; ++mi)
#pragma unroll
    for (int r = 0; r < 4; ++r) {
      const int row = wm + mi * 16 + quad * 4 + r;
#pragma unroll
      for (int ni = 0; ni < 4; ++ni) {
        float v = acc[mi][ni][r] + b1v[ni];
        v = v > 0.f ? v : 0.f;
        hS[row * 136 + wn + ni * 16 + lr] = f2bf(v);
      }
    }
  __syncthreads();

  const int cbase = (wave & 1) * 4;
  const unsigned short* pW2 =
      W2F + (((size_t)task * 8 + cbase) * 32 + blockIdx.y * 4) * 512 + lane * 8;

  f32x4 acc2[4][4];
#pragma unroll
  for (int mi = 0; mi < 4; ++mi)
#pragma unroll
    for (int ci = 0; ci < 4; ++ci) acc2[mi][ci] = (f32x4){0.f, 0.f, 0.f, 0.f};

#pragma unroll
  for (int e = 0; e < 4; ++e) {
    bf16x8 w2p[4], a2[4];
#pragma unroll
    for (int ci = 0; ci < 4; ++ci)
      w2p[ci] = *(const bf16x8*)(pW2 + ((size_t)ci * 32 + e) * 512);
#pragma unroll
    for (int mi = 0; mi < 4; ++mi)
      a2[mi] = *(const bf16x8*)&hS[(wm + mi * 16 + lr) * 136 + e * 32 + quad * 8];
#pragma unroll
    for (int mi = 0; mi < 4; ++mi)
#pragma unroll
      for (int ci = 0; ci < 4; ++ci)
        acc2[mi][ci] = __builtin_amdgcn_mfma_f32_16x16x32_bf16(
            a2[mi], w2p[ci], acc2[mi][ci], 0, 0, 0);
  }

  unsigned short* lp = Lp + ((size_t)blockIdx.y * MPAD + p0) * NCP;
#pragma unroll
  for (int mi = 0; mi < 4; ++mi)
#pragma unroll
    for (int r = 0; r < 4; ++r) {
      const int row = wm + mi * 16 + quad * 4 + r;
#pragma unroll
      for (int ci = 0; ci < 4; ++ci)
        lp[row * NCP + wn + ci * 16 + lr] = f2bf(acc2[mi][ci][r]);
    }
}

// ---------------------------------------------------------------------------
// reduce: sum 8 bf16 partial slices, +b2, scatter to out via perm. UNCHANGED.
// ---------------------------------------------------------------------------
__global__ void reduce_k(const unsigned short* __restrict__ Lp,
                         const int* __restrict__ perm,
                         const int* __restrict__ task_id,
                         const float* __restrict__ b2,
                         float* __restrict__ Out) {
  const int gid = blockIdx.x * 256 + threadIdx.x;
  const int row = gid >> 5;
  const int c4  = (gid & 31) * 4;
  if (c4 >= NC) return;
  const int og = perm[row];
  if (og < 0) return;
  float s0 = 0.f, s1 = 0.f, s2 = 0.f, s3 = 0.f;
#pragma unroll
  for (int sp = 0; sp < 8; ++sp) {
    const ushort4 v = *(const ushort4*)(Lp + ((size_t)sp * MPAD + row) * NCP + c4);
    s0 += bf2f(v.x); s1 += bf2f(v.y); s2 += bf2f(v.z); s3 += bf2f(v.w);
  }
  const int task = task_id[og];
  const float4 bb = *(const float4*)(b2 + (size_t)task * NC + c4);
  float4 o;
  o.x = s0 + bb.x; o.y = s1 + bb.y; o.z = s2 + bb.z; o.w = s3 + bb.w;
  *(float4*)(Out + (size_t)og * NC + c4) = o;
}

// ---------------------------------------------------------------------------
// Workspace layout (bytes) — total 56,688,640:
//   perm   int[9216]            @ 0           (36864)
//   gcount int[32*8]            @ 36864       (1024)
//   starts int[9]               @ 37888
//   XP     bf16[9216*1024]      @ 65536       (18874368)
//   W1T    bf16[8*1024*1024]    @ 18939904    (16777216)
//   W2F    bf16[8*8*32*512]     @ 35717120    (2097152)
//   Lp     bf16[8*9216*128]     @ 37814272    (18874368)  end 56688640
// ---------------------------------------------------------------------------
extern "C" void kernel_launch(void* const* d_in, const int* in_sizes, int n_in,
                              void* d_out, int out_size, void* d_ws, size_t ws_size,
                              hipStream_t stream) {
  const float* x       = (const float*)d_in[0];
  const int*   task_id = (const int*)d_in[1];
  const float* W1      = (const float*)d_in[2];
  const float* b1      = (const float*)d_in[3];
  const float* W2      = (const float*)d_in[4];
  const float* b2      = (const float*)d_in[5];
  float* out = (float*)d_out;

  char* ws = (char*)d_ws;
  int* perm   = (int*)(ws + 0);
  int* gcount = (int*)(ws + 36864);
  int* starts = (int*)(ws + 37888);
  unsigned short* XP  = (unsigned short*)(ws + 65536);
  unsigned short* W1T = (unsigned short*)(ws + 18939904);
  unsigned short* W2F = (unsigned short*)(ws + 35717120);
  unsigned short* Lp  = (unsigned short*)(ws + 37814272);

  count_k<<<32, 256, 0, stream>>>(task_id, gcount, perm);
  scatter_k<<<32, 256, 0, stream>>>(task_id, gcount, perm, starts);
  preproc_fused<<<GX_BLKS + W1_BLKS + W2_BLKS, 256, 0, stream>>>(
      x, perm, XP, W1, W1T, W2, W2F);
  gemm_fused4<<<dim3(MPAD / 128, HID / 128), 256, 0, stream>>>(
      XP, W1T, W2F, b1, starts, Lp);
  reduce_k<<<MPAD * 32 / 256, 256, 0, stream>>>(Lp, perm, task_id, b2, out);
}